// Round 13
// baseline (179.102 us; speedup 1.0000x reference)
//
#include <hip/hip_runtime.h>

#define N_NODES 50000
#define N_EDGES 600000
#define DIM 128
#define NCLS 10
#define ELLW 64                 // max degree (mean 12; P(>64) astronomically small)
#define CURSTRIDE 16            // one cursor per 64B line
#define EPSF 1e-15f
#define MAXNORM 0.99999f        // 1 - 1e-5
#define NTILE 782               // ceil(50000/64)
#define SPLIT 30784             // node/dst split = 481*64 (balances fill vs gather)
#define STILE 481               // SPLIT/64
#define GA_BLKS 7696            // SPLIT/4
#define GB_BLKS 4804            // (N_NODES-SPLIT)/4
#define FILLB 586               // ceil(600000/(256*4))
#define XFB 512                 // persistent transform1 blocks

typedef __attribute__((ext_vector_type(8))) short bf16x8;
typedef __attribute__((ext_vector_type(4))) float f32x4;

__device__ inline float waveSum(float v) {
#pragma unroll
  for (int o = 1; o < 64; o <<= 1) v += __shfl_xor(v, o, 64);
  return v;
}

__device__ inline unsigned short f2bf(float f) {
  union { float f; unsigned u; } c; c.f = f;
  return (unsigned short)((c.u + 0x7FFFu + ((c.u >> 16) & 1u)) >> 16);
}
__device__ inline float bf_lo(unsigned u) {
  union { unsigned u; float f; } c; c.u = u << 16; return c.f;
}
__device__ inline float bf_hi(unsigned u) {
  union { unsigned u; float f; } c; c.u = u & 0xFFFF0000u; return c.f;
}

// ================= role: ELL fill for dst in [dstLo, dstHi) =================
__device__ __forceinline__ void do_fill(
    const int* __restrict__ src, const int* __restrict__ dst,
    int* __restrict__ cursor, int* __restrict__ ell,
    int blkid, int dstLo, int dstHi)
{
  const int nthr = FILLB * 256;
  const int e = blkid * 256 + (int)threadIdx.x;
  const int e0 = e, e1 = e + nthr, e2 = e + 2 * nthr, e3 = e + 3 * nthr;
  int d0 = -1, d1 = -1, d2 = -1, d3 = -1, s0, s1, s2, s3;
  if (e0 < N_EDGES) { d0 = dst[e0]; s0 = src[e0]; }
  if (e1 < N_EDGES) { d1 = dst[e1]; s1 = src[e1]; }
  if (e2 < N_EDGES) { d2 = dst[e2]; s2 = src[e2]; }
  if (e3 < N_EDGES) { d3 = dst[e3]; s3 = src[e3]; }
  bool k0 = (d0 >= dstLo) & (d0 < dstHi);
  bool k1 = (d1 >= dstLo) & (d1 < dstHi);
  bool k2 = (d2 >= dstLo) & (d2 < dstHi);
  bool k3 = (d3 >= dstLo) & (d3 < dstHi);
  int p0, p1, p2, p3;
  if (k0) p0 = atomicAdd(&cursor[d0 * CURSTRIDE], 1);
  if (k1) p1 = atomicAdd(&cursor[d1 * CURSTRIDE], 1);
  if (k2) p2 = atomicAdd(&cursor[d2 * CURSTRIDE], 1);
  if (k3) p3 = atomicAdd(&cursor[d3 * CURSTRIDE], 1);
  if (k0) ell[d0 * ELLW + p0] = s0;
  if (k1) ell[d1 * ELLW + p1] = s1;
  if (k2) ell[d2 * ELLW + p2] = s2;
  if (k3) ell[d3 * ELLW + p3] = s3;
}

// ================= role: fused transform (MODE 0: f32 logmap in; 1: bf16 t in) ===
template <int MODE>
__device__ __forceinline__ void do_transform(
    const void* __restrict__ xin, const unsigned short* __restrict__ Wb,
    const float* __restrict__ b, unsigned short* __restrict__ y,
    unsigned short* At, int t0, int t1, int tstep)
{
  const int tid = threadIdx.x;
  const int w = tid >> 6;
  const int l = tid & 63;
  const int lr = l & 15;
  const int lg = l >> 4;

  bf16x8 bf[8][4];
#pragma unroll
  for (int n = 0; n < 8; ++n)
#pragma unroll
    for (int kc = 0; kc < 4; ++kc)
      bf[n][kc] = *(const bf16x8*)(Wb + (n * 16 + lr) * DIM + kc * 32 + lg * 8);

  float bias[8];
#pragma unroll
  for (int n = 0; n < 8; ++n) bias[n] = b[n * 16 + lr];

  const int row = w * 16 + lr;

  for (int tile = t0; tile < t1; tile += tstep) {
    const int base = tile * 64;
    const int node = base + row;
    __syncthreads();

    if (MODE == 0) {
      const float* x = (const float*)xin;
      float v[32];
      if (node < N_NODES) {
        const float4* xr = (const float4*)(x + (size_t)node * DIM + lg * 32);
#pragma unroll
        for (int q = 0; q < 8; ++q) {
          float4 f = xr[q];
          v[q * 4 + 0] = f.x; v[q * 4 + 1] = f.y; v[q * 4 + 2] = f.z; v[q * 4 + 3] = f.w;
        }
      } else {
#pragma unroll
        for (int q = 0; q < 32; ++q) v[q] = 0.f;
      }
      float sq = 0.f;
#pragma unroll
      for (int q = 0; q < 32; ++q) sq += v[q] * v[q];
      sq += __shfl_xor(sq, 16, 64);
      sq += __shfl_xor(sq, 32, 64);
      float n1 = sqrtf(sq);
      float nc = fmaxf(n1, EPSF);
      float nm = fminf(nc, MAXNORM);
      float scale = 0.5f * logf((1.f + nm) / (1.f - nm)) / nc;
#pragma unroll
      for (int s = 0; s < 4; ++s) {
        unsigned short tmp[8];
#pragma unroll
        for (int e = 0; e < 8; ++e) tmp[e] = f2bf(v[s * 8 + e] * scale);
        int byte = row * 256 + lg * 64 + s * 16;
        byte ^= (row & 7) << 4;
        *(bf16x8*)((char*)At + byte) = *(const bf16x8*)tmp;
      }
    } else {
      const unsigned short* t = (const unsigned short*)xin;
#pragma unroll
      for (int s = 0; s < 4; ++s) {
        bf16x8 frag;
        if (node < N_NODES)
          frag = *(const bf16x8*)(t + (size_t)node * DIM + lg * 32 + s * 8);
        else
          frag = bf16x8{0, 0, 0, 0, 0, 0, 0, 0};
        int byte = row * 256 + lg * 64 + s * 16;
        byte ^= (row & 7) << 4;
        *(bf16x8*)((char*)At + byte) = frag;
      }
    }
    __syncthreads();

    f32x4 acc[8];
#pragma unroll
    for (int n = 0; n < 8; ++n) {
      acc[n][0] = bias[n]; acc[n][1] = bias[n]; acc[n][2] = bias[n]; acc[n][3] = bias[n];
    }
#pragma unroll
    for (int kc = 0; kc < 4; ++kc) {
      int byte = row * 256 + kc * 64 + lg * 16;
      byte ^= (row & 7) << 4;
      bf16x8 af = *(const bf16x8*)((const char*)At + byte);
#pragma unroll
      for (int n = 0; n < 8; ++n)
        acc[n] = __builtin_amdgcn_mfma_f32_16x16x32_bf16(af, bf[n][kc], acc[n], 0, 0, 0);
    }

    float rs[4];
#pragma unroll
    for (int j = 0; j < 4; ++j) {
      float s2 = 0.f;
#pragma unroll
      for (int n = 0; n < 8; ++n) s2 += acc[n][j] * acc[n][j];
      s2 += __shfl_xor(s2, 1, 64);
      s2 += __shfl_xor(s2, 2, 64);
      s2 += __shfl_xor(s2, 4, 64);
      s2 += __shfl_xor(s2, 8, 64);
      float n2 = sqrtf(s2);
      float n2c = fmaxf(n2, EPSF);
      rs[j] = tanhf(n2c) / n2c;
    }
#pragma unroll
    for (int j = 0; j < 4; ++j) {
      int nrow = base + w * 16 + lg * 4 + j;
      if (nrow < N_NODES) {
        unsigned short* yr = y + (size_t)nrow * DIM + lr;
#pragma unroll
        for (int n = 0; n < 8; ++n) yr[n * 16] = f2bf(acc[n][j] * rs[j]);
      }
    }
  }
}

// ================= role: gather + relu + logmap0 for nodes [nodeLo+4*blk ...) ====
__device__ __forceinline__ void do_gather(
    const unsigned short* __restrict__ y, const int* __restrict__ cursor,
    const int* __restrict__ ell, unsigned short* __restrict__ tout,
    int blkid, int nodeLo, int nodeHi)
{
  const int node = nodeLo + blkid * 4 + ((int)threadIdx.x >> 6);
  if (node >= nodeHi) return;
  const int lane = threadIdx.x & 63;
  const int* lst = ell + (size_t)node * ELLW;
  const int cnt = cursor[node * CURSTRIDE];
  float2 a0 = {0.f, 0.f}, a1 = {0.f, 0.f}, a2 = {0.f, 0.f}, a3 = {0.f, 0.f};
  int j = 0;
  for (; j + 7 < cnt; j += 8) {
    unsigned u0 = ((const unsigned*)(y + (size_t)lst[j    ] * DIM))[lane];
    unsigned u1 = ((const unsigned*)(y + (size_t)lst[j + 1] * DIM))[lane];
    unsigned u2 = ((const unsigned*)(y + (size_t)lst[j + 2] * DIM))[lane];
    unsigned u3 = ((const unsigned*)(y + (size_t)lst[j + 3] * DIM))[lane];
    unsigned u4 = ((const unsigned*)(y + (size_t)lst[j + 4] * DIM))[lane];
    unsigned u5 = ((const unsigned*)(y + (size_t)lst[j + 5] * DIM))[lane];
    unsigned u6 = ((const unsigned*)(y + (size_t)lst[j + 6] * DIM))[lane];
    unsigned u7 = ((const unsigned*)(y + (size_t)lst[j + 7] * DIM))[lane];
    a0.x += bf_lo(u0); a0.y += bf_hi(u0);
    a1.x += bf_lo(u1); a1.y += bf_hi(u1);
    a2.x += bf_lo(u2); a2.y += bf_hi(u2);
    a3.x += bf_lo(u3); a3.y += bf_hi(u3);
    a0.x += bf_lo(u4); a0.y += bf_hi(u4);
    a1.x += bf_lo(u5); a1.y += bf_hi(u5);
    a2.x += bf_lo(u6); a2.y += bf_hi(u6);
    a3.x += bf_lo(u7); a3.y += bf_hi(u7);
  }
  for (; j + 3 < cnt; j += 4) {
    unsigned u0 = ((const unsigned*)(y + (size_t)lst[j    ] * DIM))[lane];
    unsigned u1 = ((const unsigned*)(y + (size_t)lst[j + 1] * DIM))[lane];
    unsigned u2 = ((const unsigned*)(y + (size_t)lst[j + 2] * DIM))[lane];
    unsigned u3 = ((const unsigned*)(y + (size_t)lst[j + 3] * DIM))[lane];
    a0.x += bf_lo(u0); a0.y += bf_hi(u0);
    a1.x += bf_lo(u1); a1.y += bf_hi(u1);
    a2.x += bf_lo(u2); a2.y += bf_hi(u2);
    a3.x += bf_lo(u3); a3.y += bf_hi(u3);
  }
  for (; j < cnt; ++j) {
    unsigned u0 = ((const unsigned*)(y + (size_t)lst[j] * DIM))[lane];
    a0.x += bf_lo(u0); a0.y += bf_hi(u0);
  }
  float2 r;
  r.x = fmaxf((a0.x + a1.x) + (a2.x + a3.x), 0.f);  // relu
  r.y = fmaxf((a0.y + a1.y) + (a2.y + a3.y), 0.f);

  float s = waveSum(r.x * r.x + r.y * r.y);
  float n = sqrtf(s);
  float nc = fmaxf(n, EPSF);
  float nm = fminf(nc, MAXNORM);
  float scale = 0.5f * logf((1.0f + nm) / (1.0f - nm)) / nc;
  unsigned u = (unsigned)f2bf(r.x * scale) | ((unsigned)f2bf(r.y * scale) << 16);
  ((unsigned*)(tout + (size_t)node * DIM))[lane] = u;
}

// ================= role: classifier head for one 64-node tile =================
__device__ __forceinline__ void do_head(
    const unsigned short* __restrict__ t2, const float* __restrict__ Wc,
    const float* __restrict__ bc, float* __restrict__ out, int tile)
{
  const int base = tile * 64;
  const int w = (int)threadIdx.x >> 6;
  const int l = threadIdx.x & 63;
  const int lr = l & 15;
  const int lg = l >> 4;

  bf16x8 bw[4];
#pragma unroll
  for (int kc = 0; kc < 4; ++kc) {
    unsigned short tmp[8];
    if (lr < NCLS) {
      const float* wr = Wc + (size_t)lr * DIM + kc * 32 + lg * 8;
#pragma unroll
      for (int e = 0; e < 8; ++e) tmp[e] = f2bf(wr[e]);
    } else {
#pragma unroll
      for (int e = 0; e < 8; ++e) tmp[e] = 0;
    }
    bw[kc] = *(const bf16x8*)tmp;
  }
  const float bias = (lr < NCLS) ? bc[lr] : 0.f;

  const int arow = base + w * 16 + lr;
  f32x4 acc;
  acc[0] = bias; acc[1] = bias; acc[2] = bias; acc[3] = bias;
#pragma unroll
  for (int kc = 0; kc < 4; ++kc) {
    bf16x8 af;
    if (arow < N_NODES)
      af = *(const bf16x8*)(t2 + (size_t)arow * DIM + kc * 32 + lg * 8);
    else
      af = bf16x8{0, 0, 0, 0, 0, 0, 0, 0};
    acc = __builtin_amdgcn_mfma_f32_16x16x32_bf16(af, bw[kc], acc, 0, 0, 0);
  }

  if (lr < NCLS) {
#pragma unroll
    for (int j = 0; j < 4; ++j) {
      int nrow = base + w * 16 + lg * 4 + j;
      if (nrow < N_NODES) out[(size_t)nrow * NCLS + lr] = acc[j];
    }
  }
}

// ======================= kernels (pipeline stages) =======================

__global__ __launch_bounds__(256) void k_init(
    int* __restrict__ cursor, const float* __restrict__ W1, const float* __restrict__ W2,
    unsigned short* __restrict__ W1b, unsigned short* __restrict__ W2b)
{
  int i = blockIdx.x * 256 + threadIdx.x;
  if (i < N_NODES) cursor[i * CURSTRIDE] = 0;
  if (i < DIM * DIM) {
    W1b[i] = f2bf(W1[i]);
    W2b[i] = f2bf(W2[i]);
  }
}

// K2: fill(dst<SPLIT) || transform1(all nodes)
__global__ __launch_bounds__(256, 3) void k_fillA_t1(
    const int* __restrict__ src, const int* __restrict__ dst,
    int* __restrict__ cursor, int* __restrict__ ell,
    const float* __restrict__ x, const unsigned short* __restrict__ W1b,
    const float* __restrict__ b1, unsigned short* __restrict__ y)
{
  __shared__ __align__(16) unsigned short At[64 * DIM];
  if (blockIdx.x < FILLB) {
    do_fill(src, dst, cursor, ell, blockIdx.x, 0, SPLIT);
  } else {
    int lb = blockIdx.x - FILLB;
    do_transform<0>(x, W1b, b1, y, At, lb, NTILE, XFB);
  }
}

// K3: fill(dst>=SPLIT) || gather1(nodes<SPLIT)
__global__ __launch_bounds__(256) void k_fillB_g1A(
    const int* __restrict__ src, const int* __restrict__ dst,
    int* __restrict__ cursor, int* __restrict__ ell,
    const unsigned short* __restrict__ y, unsigned short* __restrict__ t)
{
  if (blockIdx.x < FILLB) {
    do_fill(src, dst, cursor, ell, blockIdx.x, SPLIT, N_NODES);
  } else {
    do_gather(y, cursor, ell, t, blockIdx.x - FILLB, 0, SPLIT);
  }
}

// K4: gather1(nodes>=SPLIT, reads ybuf) || transform2(tiles<STILE, writes y2buf)
__global__ __launch_bounds__(256, 3) void k_g1B_t2A(
    const unsigned short* __restrict__ y, const int* __restrict__ cursor,
    const int* __restrict__ ell, unsigned short* __restrict__ t,
    const unsigned short* __restrict__ W2b, const float* __restrict__ b2,
    unsigned short* __restrict__ y2)
{
  __shared__ __align__(16) unsigned short At[64 * DIM];
  if (blockIdx.x < GB_BLKS) {
    do_gather(y, cursor, ell, t, blockIdx.x, SPLIT, N_NODES);
  } else {
    int tile = blockIdx.x - GB_BLKS;
    do_transform<1>(t, W2b, b2, y2, At, tile, tile + 1, 1);
  }
}

// K5: transform2(tiles>=STILE)
__global__ __launch_bounds__(256, 3) void k_t2B(
    const unsigned short* __restrict__ t, const unsigned short* __restrict__ W2b,
    const float* __restrict__ b2, unsigned short* __restrict__ y2)
{
  __shared__ __align__(16) unsigned short At[64 * DIM];
  int tile = STILE + blockIdx.x;
  do_transform<1>(t, W2b, b2, y2, At, tile, tile + 1, 1);
}

// K6: gather2(nodes<SPLIT)
__global__ __launch_bounds__(256) void k_g2A(
    const unsigned short* __restrict__ y2, const int* __restrict__ cursor,
    const int* __restrict__ ell, unsigned short* __restrict__ t2)
{
  do_gather(y2, cursor, ell, t2, blockIdx.x, 0, SPLIT);
}

// K7: gather2(nodes>=SPLIT, writes t2 rows>=SPLIT) || head(tiles<STILE, reads t2 rows<SPLIT)
__global__ __launch_bounds__(256) void k_g2B_headA(
    const unsigned short* __restrict__ y2, const int* __restrict__ cursor,
    const int* __restrict__ ell, unsigned short* __restrict__ t2,
    const float* __restrict__ Wc, const float* __restrict__ bc,
    float* __restrict__ out)
{
  if (blockIdx.x < GB_BLKS) {
    do_gather(y2, cursor, ell, t2, blockIdx.x, SPLIT, N_NODES);
  } else {
    do_head(t2, Wc, bc, out, blockIdx.x - GB_BLKS);
  }
}

// K8: head(tiles>=STILE)
__global__ __launch_bounds__(256) void k_headB(
    const unsigned short* __restrict__ t2, const float* __restrict__ Wc,
    const float* __restrict__ bc, float* __restrict__ out)
{
  do_head(t2, Wc, bc, out, STILE + blockIdx.x);
}

extern "C" void kernel_launch(void* const* d_in, const int* in_sizes, int n_in,
                              void* d_out, int out_size, void* d_ws, size_t ws_size,
                              hipStream_t stream)
{
  const int* edge = (const int*)d_in[0];
  const int* src = edge;            // edge_index[0]
  const int* dst = edge + N_EDGES;  // edge_index[1]
  const float* x  = (const float*)d_in[1];
  const float* W1 = (const float*)d_in[2];
  const float* b1 = (const float*)d_in[3];
  const float* W2 = (const float*)d_in[4];
  const float* b2 = (const float*)d_in[5];
  const float* Wc = (const float*)d_in[6];
  const float* bc = (const float*)d_in[7];
  float* out = (float*)d_out;

  unsigned short* ybuf  = (unsigned short*)d_ws;           // bf16 y1 [N, D]
  unsigned short* tbuf  = ybuf + (size_t)N_NODES * DIM;    // bf16 tangent [N, D]
  unsigned short* y2buf = tbuf + (size_t)N_NODES * DIM;    // bf16 y2 [N, D]  (fixes K4 race)
  unsigned short* W1b = y2buf + (size_t)N_NODES * DIM;
  unsigned short* W2b = W1b + DIM * DIM;
  int* cursor = (int*)(W2b + DIM * DIM);                   // N_NODES * CURSTRIDE
  int* ell = cursor + (size_t)N_NODES * CURSTRIDE;         // N_NODES * ELLW

  // K1: zero cursors + W->bf16
  k_init<<<(N_NODES + 255) / 256, 256, 0, stream>>>(cursor, W1, W2, W1b, W2b);

  // K2: fill(dst<S) || transform1(all) -> ybuf
  k_fillA_t1<<<FILLB + XFB, 256, 0, stream>>>(src, dst, cursor, ell, x, W1b, b1, ybuf);

  // K3: fill(dst>=S) || gather1(nodes<S): ybuf -> tbuf[<S]
  k_fillB_g1A<<<FILLB + GA_BLKS, 256, 0, stream>>>(src, dst, cursor, ell, ybuf, tbuf);

  // K4: gather1(nodes>=S): ybuf -> tbuf[>=S]  ||  transform2(tiles<STILE): tbuf[<S] -> y2buf[<S]
  k_g1B_t2A<<<GB_BLKS + STILE, 256, 0, stream>>>(ybuf, cursor, ell, tbuf, W2b, b2, y2buf);

  // K5: transform2(tiles>=STILE): tbuf[>=S] -> y2buf[>=S]
  k_t2B<<<NTILE - STILE, 256, 0, stream>>>(tbuf, W2b, b2, y2buf);

  // K6: gather2(nodes<S): y2buf -> tbuf[<S]
  k_g2A<<<GA_BLKS, 256, 0, stream>>>(y2buf, cursor, ell, tbuf);

  // K7: gather2(nodes>=S): y2buf -> tbuf[>=S]  ||  head(tiles<STILE): tbuf[<S] -> out
  k_g2B_headA<<<GB_BLKS + STILE, 256, 0, stream>>>(y2buf, cursor, ell, tbuf, Wc, bc, out);

  // K8: head(tiles>=STILE)
  k_headB<<<NTILE - STILE, 256, 0, stream>>>(tbuf, Wc, bc, out);
}